// Round 6
// baseline (527.237 us; speedup 1.0000x reference)
//
#include <hip/hip_runtime.h>

#define BATCH 4
#define NDIM 2048
#define EDIM 128
#define KDIM 3072
#define MDIM 8192   // BATCH*NDIM
#define HALF 15

typedef __attribute__((ext_vector_type(8))) short short8v;
typedef __attribute__((ext_vector_type(4))) float f32x4;

__device__ inline ushort bf16h(float x) {   // RNE fp32->bf16
  union { float f; unsigned u; } v; v.f = x;
  unsigned r = v.u + 0x7fff + ((v.u >> 16) & 1);
  return (ushort)(r >> 16);
}

// ---------------- K0: precompute W -> bf16 hi/lo (once; W is L3-resident) ----------------
__global__ __launch_bounds__(256)
void k_wprep(const float* __restrict__ w, ushort* __restrict__ wh, ushort* __restrict__ wl) {
  const int q = (blockIdx.x * 256 + threadIdx.x) * 4;   // 384 blocks cover 393216
  float4 v = *(const float4*)(w + q);
  const float f[4] = {v.x, v.y, v.z, v.w};
  ushort4 h, l;
  ushort* ph = (ushort*)&h; ushort* pl = (ushort*)&l;
#pragma unroll
  for (int j = 0; j < 4; ++j) {
    unsigned u = __float_as_uint(f[j]);
    ph[j] = (ushort)(u >> 16);                              // truncation hi
    pl[j] = bf16h(f[j] - __uint_as_float(u & 0xffff0000u)); // exact residual, RNE
  }
  *(ushort4*)(wh + q) = h;
  *(ushort4*)(wl + q) = l;
}

// ---------------- K1: MFMA bf16 hi/lo-split GEMM (3-term), split-K ----------------
// part[in][kc][m][e] = sum_k x[m,k]*w[e,k]
#define BMT 128   // m per block
#define BK 32     // k per step (one MFMA K)

__global__ __launch_bounds__(256, 2)
void k_gemm(const float* __restrict__ x0, const float* __restrict__ x1,
            const ushort* __restrict__ wh, const ushort* __restrict__ wl,
            float* __restrict__ part, int splitK) {
  const int tid = threadIdx.x;
  const int m0 = blockIdx.x * BMT;
  const int kc = blockIdx.y;
  const int inp = blockIdx.z;
  const float* __restrict__ x = inp ? x1 : x0;
  const int kpc = KDIM / splitK;
  const int kbeg = kc * kpc;
  const int nsteps = kpc / BK;

  __shared__ ushort sAh[BMT][BK];   // 8KB each
  __shared__ ushort sAl[BMT][BK];
  __shared__ ushort sBh[EDIM][BK];
  __shared__ ushort sBl[EDIM][BK];

  // staging map: thread t -> rows (t>>3)+32i, k-chunk (t&7)*4  (8 lanes/row)
  const int mrow = tid >> 3;
  const int c4 = (tid & 7) << 2;

  // compute map: 4 waves in 2x2 grid, each wave 64m x 64e = 4x4 fragments
  const int lane = tid & 63;
  const int wid = tid >> 6;
  const int wr = wid >> 1;
  const int wc = wid & 1;
  const int fr = lane & 15;
  const int kg = (lane >> 4) << 3;   // 0,8,16,24

  f32x4 acc[4][4];
#pragma unroll
  for (int a = 0; a < 4; ++a)
#pragma unroll
    for (int b = 0; b < 4; ++b) acc[a][b] = (f32x4){0.f, 0.f, 0.f, 0.f};

  float4 rA[4];
  ushort4 rBh[4], rBl[4];
  {
    const float* xb = x + (size_t)(m0 + mrow) * KDIM + kbeg + c4;
    const ushort* wb = wh + (size_t)mrow * KDIM + kbeg + c4;
    const ushort* wb2 = wl + (size_t)mrow * KDIM + kbeg + c4;
#pragma unroll
    for (int i = 0; i < 4; ++i) {
      rA[i]  = *(const float4*)(xb + (size_t)(32 * i) * KDIM);
      rBh[i] = *(const ushort4*)(wb + (size_t)(32 * i) * KDIM);
      rBl[i] = *(const ushort4*)(wb2 + (size_t)(32 * i) * KDIM);
    }
  }

  for (int st = 0; st < nsteps; ++st) {
    __syncthreads();   // consumers of previous tile done
#pragma unroll
    for (int i = 0; i < 4; ++i) {
      const int m = mrow + 32 * i;
      const float fa[4] = {rA[i].x, rA[i].y, rA[i].z, rA[i].w};
      ushort4 ah, al;
      ushort* pah = (ushort*)&ah; ushort* pal = (ushort*)&al;
#pragma unroll
      for (int j = 0; j < 4; ++j) {
        unsigned u = __float_as_uint(fa[j]);
        pah[j] = (ushort)(u >> 16);
        pal[j] = bf16h(fa[j] - __uint_as_float(u & 0xffff0000u));
      }
      *(ushort4*)&sAh[m][c4] = ah;
      *(ushort4*)&sAl[m][c4] = al;
      *(ushort4*)&sBh[m][c4] = rBh[i];
      *(ushort4*)&sBl[m][c4] = rBl[i];
    }
    __syncthreads();

    if (st + 1 < nsteps) {   // prefetch next tile under compute (T14)
      const int ko = kbeg + (st + 1) * BK + c4;
      const float* xb = x + (size_t)(m0 + mrow) * KDIM + ko;
      const ushort* wb = wh + (size_t)mrow * KDIM + ko;
      const ushort* wb2 = wl + (size_t)mrow * KDIM + ko;
#pragma unroll
      for (int i = 0; i < 4; ++i) {
        rA[i]  = *(const float4*)(xb + (size_t)(32 * i) * KDIM);
        rBh[i] = *(const ushort4*)(wb + (size_t)(32 * i) * KDIM);
        rBl[i] = *(const ushort4*)(wb2 + (size_t)(32 * i) * KDIM);
      }
    }

    short8v ah[4], al[4], bh[4], bl[4];
#pragma unroll
    for (int mi = 0; mi < 4; ++mi) {
      const int row = wr * 64 + mi * 16 + fr;
      ah[mi] = *(const short8v*)&sAh[row][kg];
      al[mi] = *(const short8v*)&sAl[row][kg];
    }
#pragma unroll
    for (int ei = 0; ei < 4; ++ei) {
      const int e = wc * 64 + ei * 16 + fr;
      bh[ei] = *(const short8v*)&sBh[e][kg];
      bl[ei] = *(const short8v*)&sBl[e][kg];
    }
#pragma unroll
    for (int mi = 0; mi < 4; ++mi)
#pragma unroll
      for (int ei = 0; ei < 4; ++ei) {
        acc[mi][ei] = __builtin_amdgcn_mfma_f32_16x16x32_bf16(ah[mi], bh[ei], acc[mi][ei], 0, 0, 0);
        acc[mi][ei] = __builtin_amdgcn_mfma_f32_16x16x32_bf16(ah[mi], bl[ei], acc[mi][ei], 0, 0, 0);
        acc[mi][ei] = __builtin_amdgcn_mfma_f32_16x16x32_bf16(al[mi], bh[ei], acc[mi][ei], 0, 0, 0);
      }
  }

  // C/D layout: e = lane&15, m = (lane>>4)*4 + reg   [m89-verified mapping]
  float* po = part + ((size_t)(inp * splitK + kc) * MDIM + m0) * EDIM;
#pragma unroll
  for (int mi = 0; mi < 4; ++mi) {
    const int mloc = wr * 64 + mi * 16 + ((lane >> 4) << 2);
#pragma unroll
    for (int ei = 0; ei < 4; ++ei) {
      const int e = wc * 64 + ei * 16 + fr;
#pragma unroll
      for (int r = 0; r < 4; ++r)
        po[(size_t)(mloc + r) * EDIM + e] = acc[mi][ei][r];
    }
  }
}

// ---------------- K2: reduce split-K, add bias, per-block BN partial sums ----------------
__global__ __launch_bounds__(256)
void k_reduce(const float* __restrict__ part, const float* __restrict__ bvec,
              float* __restrict__ y, float* __restrict__ spart, int splitK) {
  const int tid = threadIdx.x;
  const int in = blockIdx.z;
  const int rb = blockIdx.x;        // 128 row-blocks of 64 rows
  const int e = tid & 127;
  const int rh = tid >> 7;
  const float bb = bvec[e];
  float s = 0.f, s2 = 0.f;
  for (int rr = 0; rr < 32; ++rr) {
    const int r = rb * 64 + rh * 32 + rr;
    float v = 0.f;
    for (int kc = 0; kc < splitK; ++kc)
      v += part[((size_t)(in * splitK + kc) * MDIM + r) * EDIM + e];
    v += bb;
    y[((size_t)in * MDIM + r) * EDIM + e] = v;
    s += v; s2 += v * v;
  }
  __shared__ float l1[256], l2[256];
  l1[tid] = s; l2[tid] = s2;
  __syncthreads();
  if (rh == 0) {   // deterministic partials (no atomics -> replay-stable)
    s = l1[e] + l1[e + 128];
    s2 = l2[e] + l2[e + 128];
    spart[((size_t)(in * 128 + rb) * 2 + 0) * 128 + e] = s;
    spart[((size_t)(in * 128 + rb) * 2 + 1) * 128 + e] = s2;
  }
}

// ---------------- K3: finalize BN -> folded scale/shift ----------------
__global__ void k_finalize(const float* __restrict__ spart, const float* __restrict__ gamma,
                           const float* __restrict__ beta, float* __restrict__ scsh) {
  const int in = blockIdx.x;   // 0..1
  const int e = threadIdx.x;   // 0..127
  float s = 0.f, s2 = 0.f;
  for (int rb = 0; rb < 128; ++rb) {
    s  += spart[((size_t)(in * 128 + rb) * 2 + 0) * 128 + e];
    s2 += spart[((size_t)(in * 128 + rb) * 2 + 1) * 128 + e];
  }
  const float mu = s * (1.f / MDIM);
  const float var = s2 * (1.f / MDIM) - mu * mu;   // biased, matches reference
  const float rs = rsqrtf(var + 1e-5f);
  const float sc = gamma[e] * rs;
  const float sh = beta[e] - mu * sc;
  scsh[in * 128 + e] = sc;
  scsh[256 + in * 128 + e] = sh;
}

// ---------------- K4: apply BN + LeakyReLU(0.1) in place ----------------
__global__ __launch_bounds__(256)
void k_bnapply(float* __restrict__ y, const float* __restrict__ scsh) {
  int q = blockIdx.x * 256 + threadIdx.x;   // grid 1024 -> 262144 threads
  float4* yv = (float4*)y;
#pragma unroll
  for (int it = 0; it < 2; ++it, q += 262144) {
    float4 v = yv[q];
    const int in = q >> 18;            // 262144 float4 per input
    const int e0 = (q & 31) << 2;      // 32 float4 per row of 128
    const float* sc = scsh + in * 128 + e0;
    const float* sh = scsh + 256 + in * 128 + e0;
    float t;
    t = fmaf(sc[0], v.x, sh[0]); v.x = t >= 0.f ? t : 0.1f * t;
    t = fmaf(sc[1], v.y, sh[1]); v.y = t >= 0.f ? t : 0.1f * t;
    t = fmaf(sc[2], v.z, sh[2]); v.z = t >= 0.f ? t : 0.1f * t;
    t = fmaf(sc[3], v.w, sh[3]); v.w = t >= 0.f ? t : 0.1f * t;
    yv[q] = v;
  }
}

// ---------------- K5: banded sim + softmax; writes FULL attn rows (zeros+band) + compact band ----------------
__global__ __launch_bounds__(256)
void k_sim(const float* __restrict__ y, float* __restrict__ attn, float* __restrict__ aw) {
  const int tid = threadIdx.x;
  const int row = blockIdx.x * 4 + (tid >> 6);   // b*N+i, one wave per row
  const int lane = tid & 63;
  const int b = row >> 11;
  const int i = row & 2047;
  const int jlo = max(0, i - HALF);
  const int jhi = min(NDIM - 1, i + HALF);
  const int j = jlo + lane;
  const bool valid = (lane < 31) && (j <= jhi);
  const int jc = valid ? j : jlo;
  const float* __restrict__ xr = y + (size_t)row * EDIM;
  const float* __restrict__ tr = y + (size_t)MDIM * EDIM + ((size_t)(b << 11) + jc) * EDIM;
  float s = 0.f;
#pragma unroll
  for (int e = 0; e < EDIM; e += 4) {
    float4 u = *(const float4*)(xr + e);   // uniform -> broadcast
    float4 v = *(const float4*)(tr + e);   // per-lane row
    s = fmaf(u.x, v.x, s); s = fmaf(u.y, v.y, s);
    s = fmaf(u.z, v.z, s); s = fmaf(u.w, v.w, s);
  }
  float sm = valid ? s : -1e30f;
  float mx = sm;
#pragma unroll
  for (int o = 1; o < 64; o <<= 1) mx = fmaxf(mx, __shfl_xor(mx, o));
  const float p = valid ? __expf(sm - mx) : 0.f;
  float ss = p;
#pragma unroll
  for (int o = 1; o < 64; o <<= 1) ss += __shfl_xor(ss, o);
  const float a = p / ss;   // lanes >= 31: p=0 -> a=0

  // full-row write (replaces global memset): zeros outside band, shfl'd weights inside
  float* orow = attn + (size_t)row * NDIM;
  const int bw = jhi - jlo;   // band width - 1 (<= 30)
  for (int c0 = lane << 2; c0 < NDIM; c0 += 256) {
    float4 v;
    float* pv = (float*)&v;
#pragma unroll
    for (int t = 0; t < 4; ++t) {
      const int d = c0 + t - jlo;
      const float val = __shfl(a, d & 63);
      pv[t] = (d >= 0 && d <= bw) ? val : 0.f;
    }
    *(float4*)(orow + c0) = v;
  }
  if (lane < 32) aw[(size_t)row * 32 + lane] = valid ? a : 0.f;
}

// ---------------- K6: banded attn @ mem + blend with sig ----------------
#define TI 16
#define TJMAX 46
#define FC 256

__global__ __launch_bounds__(256, 2)
void k_memw(const float* __restrict__ sig, const float* __restrict__ mem,
            const float* __restrict__ aw, float* __restrict__ out) {
  const int tid = threadIdx.x;
  const int fc0 = blockIdx.x * FC;
  const int i0 = blockIdx.y * TI;
  const int b = blockIdx.z;
  const int jlo = max(0, i0 - HALF);
  const int jhi = min(NDIM - 1, i0 + TI - 1 + HALF);
  const int tj = jhi - jlo + 1;     // <= 46

  __shared__ float sV[TJMAX][FC];   // mem rows (f-chunk)
  __shared__ float sWt[TJMAX][TI];  // band weights, zeros outside band

  for (int idx = tid; idx < tj * TI; idx += 256) {
    const int jj = idx >> 4;
    const int ii = idx & 15;
    const int ii_g = i0 + ii;
    const int jg = jlo + jj;
    const int jli = max(0, ii_g - HALF);
    const int jhii = min(NDIM - 1, ii_g + HALF);
    float wv = 0.f;
    if (jg >= jli && jg <= jhii) wv = aw[(size_t)((b << 11) + ii_g) * 32 + (jg - jli)];
    sWt[jj][ii] = wv;
  }
  for (int idx = tid; idx < tj * (FC / 4); idx += 256) {
    const int jj = idx >> 6;
    const int f4 = idx & 63;
    *(float4*)&sV[jj][f4 << 2] =
        *(const float4*)(mem + (size_t)((b << 11) + jlo + jj) * KDIM + fc0 + (f4 << 2));
  }
  __syncthreads();

  const int ig = tid >> 6;          // wave id -> 4 i rows
  const int fg = tid & 63;          // lane -> 4 f
  const int ibase = i0 + (ig << 2);
  const int wlo = max(jlo, ibase - HALF) - jlo;
  const int whi = min(jhi, ibase + 3 + HALF) - jlo;

  float acc[4][4];
#pragma unroll
  for (int a = 0; a < 4; ++a)
#pragma unroll
    for (int c = 0; c < 4; ++c) acc[a][c] = 0.f;

  for (int jj = wlo; jj <= whi; ++jj) {   // <= 34 iters, wave-uniform bounds
    float4 wv = *(const float4*)&sWt[jj][ig << 2];   // wave-uniform -> broadcast
    float4 vv = *(const float4*)&sV[jj][fg << 2];    // consecutive -> conflict-free
    const float wa[4] = {wv.x, wv.y, wv.z, wv.w};
    const float va[4] = {vv.x, vv.y, vv.z, vv.w};
#pragma unroll
    for (int mi = 0; mi < 4; ++mi)
#pragma unroll
      for (int fi = 0; fi < 4; ++fi)
        acc[mi][fi] = fmaf(wa[mi], va[fi], acc[mi][fi]);
  }

  const size_t base = (size_t)((b << 11) + ibase) * KDIM + fc0 + (fg << 2);
#pragma unroll
  for (int mi = 0; mi < 4; ++mi) {
    float4 sv = *(const float4*)(sig + base + (size_t)mi * KDIM);
    float4 ov;
    ov.x = 0.5f * sv.x + 0.5f * acc[mi][0];
    ov.y = 0.5f * sv.y + 0.5f * acc[mi][1];
    ov.z = 0.5f * sv.z + 0.5f * acc[mi][2];
    ov.w = 0.5f * sv.w + 0.5f * acc[mi][3];
    *(float4*)(out + base + (size_t)mi * KDIM) = ov;
  }
}

extern "C" void kernel_launch(void* const* d_in, const int* in_sizes, int n_in,
                              void* d_out, int out_size, void* d_ws, size_t ws_size,
                              hipStream_t stream) {
  const float* sig   = (const float*)d_in[0];
  const float* mem   = (const float*)d_in[1];
  const float* w     = (const float*)d_in[2];
  const float* bv    = (const float*)d_in[3];
  const float* gamma = (const float*)d_in[4];
  const float* beta  = (const float*)d_in[5];

  float* out_mem  = (float*)d_out;
  float* out_attn = out_mem + (size_t)BATCH * NDIM * KDIM;   // 25,165,824

  float* wsf = (float*)d_ws;
  const size_t ME = (size_t)MDIM * EDIM;                      // 1,048,576
  // fixed tail (floats): y(2ME) + spart(65536) + scsh(512) + aw(262144) + Wh/Wl(196608)
  const size_t fixed = 2 * ME + 65536 + 512 + 262144 + 196608;
  int splitK = 8;
  while (splitK > 1 && ((size_t)2 * splitK * ME + fixed) * 4 > ws_size) splitK >>= 1;

  float* part  = wsf;
  float* y     = part + (size_t)2 * splitK * ME;
  float* spart = y + 2 * ME;
  float* scsh  = spart + 65536;
  float* aw    = scsh + 512;
  ushort* wh   = (ushort*)(aw + 262144);
  ushort* wl   = wh + (size_t)EDIM * KDIM;

  hipLaunchKernelGGL(k_wprep, dim3(EDIM * KDIM / 1024), dim3(256), 0, stream, w, wh, wl);

  dim3 g1(MDIM / BMT, splitK, 2);
  hipLaunchKernelGGL(k_gemm, g1, dim3(256), 0, stream, sig, mem, wh, wl, part, splitK);

  dim3 g2(MDIM / 64, 1, 2);
  hipLaunchKernelGGL(k_reduce, g2, dim3(256), 0, stream, part, bv, y, spart, splitK);

  hipLaunchKernelGGL(k_finalize, dim3(2), dim3(128), 0, stream, spart, gamma, beta, scsh);

  hipLaunchKernelGGL(k_bnapply, dim3(1024), dim3(256), 0, stream, y, scsh);

  hipLaunchKernelGGL(k_sim, dim3(MDIM / 4), dim3(256), 0, stream, y, out_attn, aw);

  dim3 g6(KDIM / FC, NDIM / TI, BATCH);
  hipLaunchKernelGGL(k_memw, g6, dim3(256), 0, stream, sig, mem, aw, out_mem);
}

// Round 9
// 477.117 us; speedup vs baseline: 1.1050x; 1.1050x over previous
//
#include <hip/hip_runtime.h>

#define BATCH 4
#define NDIM 2048
#define EDIM 128
#define KDIM 3072
#define MDIM 8192   // BATCH*NDIM
#define HALF 15

typedef __attribute__((ext_vector_type(8))) short short8v;
typedef __attribute__((ext_vector_type(4))) float f32x4;

__device__ inline ushort bf16h(float x) {   // RNE fp32->bf16
  union { float f; unsigned u; } v; v.f = x;
  unsigned r = v.u + 0x7fff + ((v.u >> 16) & 1);
  return (ushort)(r >> 16);
}

// ---------------- K0: precompute W -> bf16 hi/lo (once; W is L3-resident) ----------------
__global__ __launch_bounds__(256)
void k_wprep(const float* __restrict__ w, ushort* __restrict__ wh, ushort* __restrict__ wl) {
  const int q = (blockIdx.x * 256 + threadIdx.x) * 4;   // 384 blocks cover 393216
  float4 v = *(const float4*)(w + q);
  const float f[4] = {v.x, v.y, v.z, v.w};
  ushort4 h, l;
  ushort* ph = (ushort*)&h; ushort* pl = (ushort*)&l;
#pragma unroll
  for (int j = 0; j < 4; ++j) {
    unsigned u = __float_as_uint(f[j]);
    ph[j] = (ushort)(u >> 16);                              // truncation hi
    pl[j] = bf16h(f[j] - __uint_as_float(u & 0xffff0000u)); // exact residual, RNE
  }
  *(ushort4*)(wh + q) = h;
  *(ushort4*)(wl + q) = l;
}

// ---------------- K1: MFMA bf16 hi/lo-split GEMM (3-term), split-K ----------------
// part[in][kc][m][e] = sum_k x[m,k]*w[e,k]
#define BMT 128   // m per block
#define BK 32     // k per step (one MFMA K)

__global__ __launch_bounds__(256, 2)
void k_gemm(const float* __restrict__ x0, const float* __restrict__ x1,
            const ushort* __restrict__ wh, const ushort* __restrict__ wl,
            float* __restrict__ part, int splitK) {
  const int tid = threadIdx.x;
  const int m0 = blockIdx.x * BMT;
  const int kc = blockIdx.y;
  const int inp = blockIdx.z;
  const float* __restrict__ x = inp ? x1 : x0;
  const int kpc = KDIM / splitK;
  const int kbeg = kc * kpc;
  const int nsteps = kpc / BK;

  __shared__ ushort sAh[BMT][BK];   // 8KB each
  __shared__ ushort sAl[BMT][BK];
  __shared__ ushort sBh[EDIM][BK];
  __shared__ ushort sBl[EDIM][BK];

  // staging map: thread t -> rows (t>>3)+32i, k-chunk (t&7)*4  (8 lanes/row)
  const int mrow = tid >> 3;
  const int c4 = (tid & 7) << 2;

  // compute map: 4 waves in 2x2 grid, each wave 64m x 64e = 4x4 fragments
  const int lane = tid & 63;
  const int wid = tid >> 6;
  const int wr = wid >> 1;
  const int wc = wid & 1;
  const int fr = lane & 15;
  const int kg = (lane >> 4) << 3;   // 0,8,16,24

  f32x4 acc[4][4];
#pragma unroll
  for (int a = 0; a < 4; ++a)
#pragma unroll
    for (int b = 0; b < 4; ++b) acc[a][b] = (f32x4){0.f, 0.f, 0.f, 0.f};

  float4 rA[4];
  ushort4 rBh[4], rBl[4];
  {
    const float* xb = x + (size_t)(m0 + mrow) * KDIM + kbeg + c4;
    const ushort* wb = wh + (size_t)mrow * KDIM + kbeg + c4;
    const ushort* wb2 = wl + (size_t)mrow * KDIM + kbeg + c4;
#pragma unroll
    for (int i = 0; i < 4; ++i) {
      rA[i]  = *(const float4*)(xb + (size_t)(32 * i) * KDIM);
      rBh[i] = *(const ushort4*)(wb + (size_t)(32 * i) * KDIM);
      rBl[i] = *(const ushort4*)(wb2 + (size_t)(32 * i) * KDIM);
    }
  }

  for (int st = 0; st < nsteps; ++st) {
    __syncthreads();   // consumers of previous tile done
#pragma unroll
    for (int i = 0; i < 4; ++i) {
      const int m = mrow + 32 * i;
      const float fa[4] = {rA[i].x, rA[i].y, rA[i].z, rA[i].w};
      ushort4 ah, al;
      ushort* pah = (ushort*)&ah; ushort* pal = (ushort*)&al;
#pragma unroll
      for (int j = 0; j < 4; ++j) {
        unsigned u = __float_as_uint(fa[j]);
        pah[j] = (ushort)(u >> 16);
        pal[j] = bf16h(fa[j] - __uint_as_float(u & 0xffff0000u));
      }
      *(ushort4*)&sAh[m][c4] = ah;
      *(ushort4*)&sAl[m][c4] = al;
      *(ushort4*)&sBh[m][c4] = rBh[i];
      *(ushort4*)&sBl[m][c4] = rBl[i];
    }
    __syncthreads();

    if (st + 1 < nsteps) {   // prefetch next tile under compute (T14)
      const int ko = kbeg + (st + 1) * BK + c4;
      const float* xb = x + (size_t)(m0 + mrow) * KDIM + ko;
      const ushort* wb = wh + (size_t)mrow * KDIM + ko;
      const ushort* wb2 = wl + (size_t)mrow * KDIM + ko;
#pragma unroll
      for (int i = 0; i < 4; ++i) {
        rA[i]  = *(const float4*)(xb + (size_t)(32 * i) * KDIM);
        rBh[i] = *(const ushort4*)(wb + (size_t)(32 * i) * KDIM);
        rBl[i] = *(const ushort4*)(wb2 + (size_t)(32 * i) * KDIM);
      }
    }

    short8v ah[4], al[4], bh[4], bl[4];
#pragma unroll
    for (int mi = 0; mi < 4; ++mi) {
      const int row = wr * 64 + mi * 16 + fr;
      ah[mi] = *(const short8v*)&sAh[row][kg];
      al[mi] = *(const short8v*)&sAl[row][kg];
    }
#pragma unroll
    for (int ei = 0; ei < 4; ++ei) {
      const int e = wc * 64 + ei * 16 + fr;
      bh[ei] = *(const short8v*)&sBh[e][kg];
      bl[ei] = *(const short8v*)&sBl[e][kg];
    }
#pragma unroll
    for (int mi = 0; mi < 4; ++mi)
#pragma unroll
      for (int ei = 0; ei < 4; ++ei) {
        acc[mi][ei] = __builtin_amdgcn_mfma_f32_16x16x32_bf16(ah[mi], bh[ei], acc[mi][ei], 0, 0, 0);
        acc[mi][ei] = __builtin_amdgcn_mfma_f32_16x16x32_bf16(ah[mi], bl[ei], acc[mi][ei], 0, 0, 0);
        acc[mi][ei] = __builtin_amdgcn_mfma_f32_16x16x32_bf16(al[mi], bh[ei], acc[mi][ei], 0, 0, 0);
      }
  }

  // C/D layout: e = lane&15, m = (lane>>4)*4 + reg   [m89-verified mapping]
  float* po = part + ((size_t)(inp * splitK + kc) * MDIM + m0) * EDIM;
#pragma unroll
  for (int mi = 0; mi < 4; ++mi) {
    const int mloc = wr * 64 + mi * 16 + ((lane >> 4) << 2);
#pragma unroll
    for (int ei = 0; ei < 4; ++ei) {
      const int e = wc * 64 + ei * 16 + fr;
#pragma unroll
      for (int r = 0; r < 4; ++r)
        po[(size_t)(mloc + r) * EDIM + e] = acc[mi][ei][r];
    }
  }
}

// ---------------- K2: reduce split-K, add bias, per-block BN partial sums ----------------
__global__ __launch_bounds__(256)
void k_reduce(const float* __restrict__ part, const float* __restrict__ bvec,
              float* __restrict__ y, float* __restrict__ spart, int splitK) {
  const int tid = threadIdx.x;
  const int in = blockIdx.z;
  const int rb = blockIdx.x;        // 128 row-blocks of 64 rows
  const int e = tid & 127;
  const int rh = tid >> 7;
  const float bb = bvec[e];
  float s = 0.f, s2 = 0.f;
  for (int rr = 0; rr < 32; ++rr) {
    const int r = rb * 64 + rh * 32 + rr;
    float v = 0.f;
    for (int kc = 0; kc < splitK; ++kc)
      v += part[((size_t)(in * splitK + kc) * MDIM + r) * EDIM + e];
    v += bb;
    y[((size_t)in * MDIM + r) * EDIM + e] = v;
    s += v; s2 += v * v;
  }
  __shared__ float l1[256], l2[256];
  l1[tid] = s; l2[tid] = s2;
  __syncthreads();
  if (rh == 0) {   // deterministic partials (no atomics -> replay-stable)
    s = l1[e] + l1[e + 128];
    s2 = l2[e] + l2[e + 128];
    spart[((size_t)(in * 128 + rb) * 2 + 0) * 128 + e] = s;
    spart[((size_t)(in * 128 + rb) * 2 + 1) * 128 + e] = s2;
  }
}

// ---------------- K3: finalize BN -> folded scale/shift ----------------
__global__ void k_finalize(const float* __restrict__ spart, const float* __restrict__ gamma,
                           const float* __restrict__ beta, float* __restrict__ scsh) {
  const int in = blockIdx.x;   // 0..1
  const int e = threadIdx.x;   // 0..127
  float s = 0.f, s2 = 0.f;
  for (int rb = 0; rb < 128; ++rb) {
    s  += spart[((size_t)(in * 128 + rb) * 2 + 0) * 128 + e];
    s2 += spart[((size_t)(in * 128 + rb) * 2 + 1) * 128 + e];
  }
  const float mu = s * (1.f / MDIM);
  const float var = s2 * (1.f / MDIM) - mu * mu;   // biased, matches reference
  const float rs = rsqrtf(var + 1e-5f);
  const float sc = gamma[e] * rs;
  const float sh = beta[e] - mu * sc;
  scsh[in * 128 + e] = sc;
  scsh[256 + in * 128 + e] = sh;
}

// ---------------- K4: apply BN + LeakyReLU(0.1) in place ----------------
__global__ __launch_bounds__(256)
void k_bnapply(float* __restrict__ y, const float* __restrict__ scsh) {
  int q = blockIdx.x * 256 + threadIdx.x;   // grid 1024 -> 262144 threads
  float4* yv = (float4*)y;
#pragma unroll
  for (int it = 0; it < 2; ++it, q += 262144) {
    float4 v = yv[q];
    const int in = q >> 18;            // 262144 float4 per input
    const int e0 = (q & 31) << 2;      // 32 float4 per row of 128
    const float* sc = scsh + in * 128 + e0;
    const float* sh = scsh + 256 + in * 128 + e0;
    float t;
    t = fmaf(sc[0], v.x, sh[0]); v.x = t >= 0.f ? t : 0.1f * t;
    t = fmaf(sc[1], v.y, sh[1]); v.y = t >= 0.f ? t : 0.1f * t;
    t = fmaf(sc[2], v.z, sh[2]); v.z = t >= 0.f ? t : 0.1f * t;
    t = fmaf(sc[3], v.w, sh[3]); v.w = t >= 0.f ? t : 0.1f * t;
    yv[q] = v;
  }
}

// ---------------- K5: banded sim + softmax; writes FULL attn rows (zeros+band) + compact band ----------------
__global__ __launch_bounds__(256)
void k_sim(const float* __restrict__ y, float* __restrict__ attn, float* __restrict__ aw) {
  const int tid = threadIdx.x;
  const int row = blockIdx.x * 4 + (tid >> 6);   // b*N+i, one wave per row
  const int lane = tid & 63;
  const int b = row >> 11;
  const int i = row & 2047;
  const int jlo = max(0, i - HALF);
  const int jhi = min(NDIM - 1, i + HALF);
  const int j = jlo + lane;
  const bool valid = (lane < 31) && (j <= jhi);
  const int jc = valid ? j : jlo;
  const float* __restrict__ xr = y + (size_t)row * EDIM;
  const float* __restrict__ tr = y + (size_t)MDIM * EDIM + ((size_t)(b << 11) + jc) * EDIM;
  float s = 0.f;
#pragma unroll
  for (int e = 0; e < EDIM; e += 4) {
    float4 u = *(const float4*)(xr + e);   // uniform -> broadcast
    float4 v = *(const float4*)(tr + e);   // per-lane row
    s = fmaf(u.x, v.x, s); s = fmaf(u.y, v.y, s);
    s = fmaf(u.z, v.z, s); s = fmaf(u.w, v.w, s);
  }
  float sm = valid ? s : -1e30f;
  float mx = sm;
#pragma unroll
  for (int o = 1; o < 64; o <<= 1) mx = fmaxf(mx, __shfl_xor(mx, o));
  const float p = valid ? __expf(sm - mx) : 0.f;
  float ss = p;
#pragma unroll
  for (int o = 1; o < 64; o <<= 1) ss += __shfl_xor(ss, o);
  const float a = p / ss;   // lanes >= 31: p=0 -> a=0

  // full-row write (replaces global memset): zeros outside band, shfl'd weights inside
  float* orow = attn + (size_t)row * NDIM;
  const int bw = jhi - jlo;   // band width - 1 (<= 30)
  for (int c0 = lane << 2; c0 < NDIM; c0 += 256) {
    float4 v;
    float* pv = (float*)&v;
#pragma unroll
    for (int t = 0; t < 4; ++t) {
      const int d = c0 + t - jlo;
      const float val = __shfl(a, d & 63);
      pv[t] = (d >= 0 && d <= bw) ? val : 0.f;
    }
    *(float4*)(orow + c0) = v;
  }
  if (lane < 32) aw[(size_t)row * 32 + lane] = valid ? a : 0.f;
}

// ---------------- K6: banded attn @ mem + blend with sig ----------------
// 1D grid, XCD-chunked: same-XCD consecutive blocks walk i-tiles within one
// (fc,b) slab -> halo rows (30/46) and the 2MB mem slab stay hot in that XCD's L2.
#define TI 16
#define TJMAX 46
#define FC 256
#define NIT (NDIM / TI)          // 128 i-tiles
#define NFC (KDIM / FC)          // 12 f-chunks
#define NWG_MEMW (NIT * NFC * BATCH)   // 6144, divisible by 8

__global__ __launch_bounds__(256, 2)
void k_memw(const float* __restrict__ sig, const float* __restrict__ mem,
            const float* __restrict__ aw, float* __restrict__ out) {
  const int tid = threadIdx.x;
  // bijective XCD-chunked remap (nwg % 8 == 0)
  const int bid = blockIdx.x;
  const int nid = (bid & 7) * (NWG_MEMW / 8) + (bid >> 3);
  const int b  = nid / (NIT * NFC);
  const int r  = nid % (NIT * NFC);
  const int fc0 = (r / NIT) * FC;
  const int i0  = (r % NIT) * TI;      // i fastest within same-XCD chunk
  const int jlo = max(0, i0 - HALF);
  const int jhi = min(NDIM - 1, i0 + TI - 1 + HALF);
  const int tj = jhi - jlo + 1;     // <= 46

  __shared__ float sV[TJMAX][FC];   // mem rows (f-chunk)
  __shared__ float sWt[TJMAX][TI];  // band weights, zeros outside band

  for (int idx = tid; idx < tj * TI; idx += 256) {
    const int jj = idx >> 4;
    const int ii = idx & 15;
    const int ii_g = i0 + ii;
    const int jg = jlo + jj;
    const int jli = max(0, ii_g - HALF);
    const int jhii = min(NDIM - 1, ii_g + HALF);
    float wv = 0.f;
    if (jg >= jli && jg <= jhii) wv = aw[(size_t)((b << 11) + ii_g) * 32 + (jg - jli)];
    sWt[jj][ii] = wv;
  }
  for (int idx = tid; idx < tj * (FC / 4); idx += 256) {
    const int jj = idx >> 6;
    const int f4 = idx & 63;
    *(float4*)&sV[jj][f4 << 2] =
        *(const float4*)(mem + (size_t)((b << 11) + jlo + jj) * KDIM + fc0 + (f4 << 2));
  }
  __syncthreads();

  const int ig = tid >> 6;          // wave id -> 4 i rows
  const int fg = tid & 63;          // lane -> 4 f
  const int ibase = i0 + (ig << 2);
  const int wlo = max(jlo, ibase - HALF) - jlo;
  const int whi = min(jhi, ibase + 3 + HALF) - jlo;

  float acc[4][4];
#pragma unroll
  for (int a = 0; a < 4; ++a)
#pragma unroll
    for (int c = 0; c < 4; ++c) acc[a][c] = 0.f;

  for (int jj = wlo; jj <= whi; ++jj) {   // <= 34 iters, wave-uniform bounds
    float4 wv = *(const float4*)&sWt[jj][ig << 2];   // wave-uniform -> broadcast
    float4 vv = *(const float4*)&sV[jj][fg << 2];    // consecutive -> conflict-free
    const float wa[4] = {wv.x, wv.y, wv.z, wv.w};
    const float va[4] = {vv.x, vv.y, vv.z, vv.w};
#pragma unroll
    for (int mi = 0; mi < 4; ++mi)
#pragma unroll
      for (int fi = 0; fi < 4; ++fi)
        acc[mi][fi] = fmaf(wa[mi], va[fi], acc[mi][fi]);
  }

  const size_t base = (size_t)((b << 11) + ibase) * KDIM + fc0 + (fg << 2);
#pragma unroll
  for (int mi = 0; mi < 4; ++mi) {
    float4 sv = *(const float4*)(sig + base + (size_t)mi * KDIM);
    float4 ov;
    ov.x = 0.5f * sv.x + 0.5f * acc[mi][0];
    ov.y = 0.5f * sv.y + 0.5f * acc[mi][1];
    ov.z = 0.5f * sv.z + 0.5f * acc[mi][2];
    ov.w = 0.5f * sv.w + 0.5f * acc[mi][3];
    *(float4*)(out + base + (size_t)mi * KDIM) = ov;
  }
}

extern "C" void kernel_launch(void* const* d_in, const int* in_sizes, int n_in,
                              void* d_out, int out_size, void* d_ws, size_t ws_size,
                              hipStream_t stream) {
  const float* sig   = (const float*)d_in[0];
  const float* mem   = (const float*)d_in[1];
  const float* w     = (const float*)d_in[2];
  const float* bv    = (const float*)d_in[3];
  const float* gamma = (const float*)d_in[4];
  const float* beta  = (const float*)d_in[5];

  float* out_mem  = (float*)d_out;
  float* out_attn = out_mem + (size_t)BATCH * NDIM * KDIM;   // 25,165,824

  float* wsf = (float*)d_ws;
  const size_t ME = (size_t)MDIM * EDIM;                      // 1,048,576
  // fixed tail (floats): y(2ME) + spart(65536) + scsh(512) + aw(262144) + Wh/Wl(196608)
  const size_t fixed = 2 * ME + 65536 + 512 + 262144 + 196608;
  int splitK = 4;   // R5 measured: splitK=8 regresses (2x epilogue writes, no occupancy gain)
  while (splitK > 1 && ((size_t)2 * splitK * ME + fixed) * 4 > ws_size) splitK >>= 1;

  float* part  = wsf;
  float* y     = part + (size_t)2 * splitK * ME;
  float* spart = y + 2 * ME;
  float* scsh  = spart + 65536;
  float* aw    = scsh + 512;
  ushort* wh   = (ushort*)(aw + 262144);
  ushort* wl   = wh + (size_t)EDIM * KDIM;

  hipLaunchKernelGGL(k_wprep, dim3(EDIM * KDIM / 1024), dim3(256), 0, stream, w, wh, wl);

  dim3 g1(MDIM / BMT, splitK, 2);
  hipLaunchKernelGGL(k_gemm, g1, dim3(256), 0, stream, sig, mem, wh, wl, part, splitK);

  dim3 g2(MDIM / 64, 1, 2);
  hipLaunchKernelGGL(k_reduce, g2, dim3(256), 0, stream, part, bv, y, spart, splitK);

  hipLaunchKernelGGL(k_finalize, dim3(2), dim3(128), 0, stream, spart, gamma, beta, scsh);

  hipLaunchKernelGGL(k_bnapply, dim3(1024), dim3(256), 0, stream, y, scsh);

  hipLaunchKernelGGL(k_sim, dim3(MDIM / 4), dim3(256), 0, stream, y, out_attn, aw);

  hipLaunchKernelGGL(k_memw, dim3(NWG_MEMW), dim3(256), 0, stream, sig, mem, aw, out_mem);
}

// Round 10
// 473.966 us; speedup vs baseline: 1.1124x; 1.0066x over previous
//
#include <hip/hip_runtime.h>

#define BATCH 4
#define NDIM 2048
#define EDIM 128
#define KDIM 3072
#define MDIM 8192   // BATCH*NDIM
#define HALF 15

typedef __attribute__((ext_vector_type(8))) short short8v;
typedef __attribute__((ext_vector_type(4))) float f32x4;

__device__ inline ushort bf16h(float x) {   // RNE fp32->bf16
  union { float f; unsigned u; } v; v.f = x;
  unsigned r = v.u + 0x7fff + ((v.u >> 16) & 1);
  return (ushort)(r >> 16);
}

// ---------------- K0: precompute W -> bf16 hi/lo (once; W is L3-resident) ----------------
__global__ __launch_bounds__(256)
void k_wprep(const float* __restrict__ w, ushort* __restrict__ wh, ushort* __restrict__ wl) {
  const int q = (blockIdx.x * 256 + threadIdx.x) * 4;   // 384 blocks cover 393216
  float4 v = *(const float4*)(w + q);
  const float f[4] = {v.x, v.y, v.z, v.w};
  ushort4 h, l;
  ushort* ph = (ushort*)&h; ushort* pl = (ushort*)&l;
#pragma unroll
  for (int j = 0; j < 4; ++j) {
    unsigned u = __float_as_uint(f[j]);
    ph[j] = (ushort)(u >> 16);                              // truncation hi
    pl[j] = bf16h(f[j] - __uint_as_float(u & 0xffff0000u)); // exact residual, RNE
  }
  *(ushort4*)(wh + q) = h;
  *(ushort4*)(wl + q) = l;
}

// ---------------- K1: MFMA bf16 hi/lo-split GEMM (3-term), split-K ----------------
// BMT=64: grid 1024 blocks -> 4-5 blocks/CU (R8: 512 blocks capped occupancy at 18%)
#define BMT 64
#define BK 32     // k per step (one MFMA K)

__global__ __launch_bounds__(256, 4)
void k_gemm(const float* __restrict__ x0, const float* __restrict__ x1,
            const ushort* __restrict__ wh, const ushort* __restrict__ wl,
            float* __restrict__ part, int splitK) {
  const int tid = threadIdx.x;
  const int m0 = blockIdx.x * BMT;
  const int kc = blockIdx.y;
  const int inp = blockIdx.z;
  const float* __restrict__ x = inp ? x1 : x0;
  const int kpc = KDIM / splitK;
  const int kbeg = kc * kpc;
  const int nsteps = kpc / BK;

  __shared__ ushort sAh[BMT][BK];   // 4KB each
  __shared__ ushort sAl[BMT][BK];
  __shared__ ushort sBh[EDIM][BK];  // 8KB each
  __shared__ ushort sBl[EDIM][BK];

  // staging map: thread t -> row (t>>3)+32i, k-chunk (t&7)*4  (8 lanes/row)
  const int mrow = tid >> 3;
  const int c4 = (tid & 7) << 2;

  // compute map: 4 waves in 2x2 grid; wave = 32m x 64e = 2x4 fragments
  const int lane = tid & 63;
  const int wid = tid >> 6;
  const int wr = wid >> 1;
  const int wc = wid & 1;
  const int fr = lane & 15;
  const int kg = (lane >> 4) << 3;   // 0,8,16,24

  f32x4 acc[2][4];
#pragma unroll
  for (int a = 0; a < 2; ++a)
#pragma unroll
    for (int b = 0; b < 4; ++b) acc[a][b] = (f32x4){0.f, 0.f, 0.f, 0.f};

  float4 rA[2];
  ushort4 rBh[4], rBl[4];
  {
    const float* xb = x + (size_t)(m0 + mrow) * KDIM + kbeg + c4;
    const ushort* wb = wh + (size_t)mrow * KDIM + kbeg + c4;
    const ushort* wb2 = wl + (size_t)mrow * KDIM + kbeg + c4;
#pragma unroll
    for (int i = 0; i < 2; ++i)
      rA[i] = *(const float4*)(xb + (size_t)(32 * i) * KDIM);
#pragma unroll
    for (int i = 0; i < 4; ++i) {
      rBh[i] = *(const ushort4*)(wb + (size_t)(32 * i) * KDIM);
      rBl[i] = *(const ushort4*)(wb2 + (size_t)(32 * i) * KDIM);
    }
  }

  for (int st = 0; st < nsteps; ++st) {
    __syncthreads();   // consumers of previous tile done
#pragma unroll
    for (int i = 0; i < 2; ++i) {
      const int m = mrow + 32 * i;
      const float fa[4] = {rA[i].x, rA[i].y, rA[i].z, rA[i].w};
      ushort4 ah, al;
      ushort* pah = (ushort*)&ah; ushort* pal = (ushort*)&al;
#pragma unroll
      for (int j = 0; j < 4; ++j) {
        unsigned u = __float_as_uint(fa[j]);
        pah[j] = (ushort)(u >> 16);
        pal[j] = bf16h(fa[j] - __uint_as_float(u & 0xffff0000u));
      }
      *(ushort4*)&sAh[m][c4] = ah;
      *(ushort4*)&sAl[m][c4] = al;
    }
#pragma unroll
    for (int i = 0; i < 4; ++i) {
      const int m = mrow + 32 * i;
      *(ushort4*)&sBh[m][c4] = rBh[i];
      *(ushort4*)&sBl[m][c4] = rBl[i];
    }
    __syncthreads();

    if (st + 1 < nsteps) {   // prefetch next tile under compute (T14)
      const int ko = kbeg + (st + 1) * BK + c4;
      const float* xb = x + (size_t)(m0 + mrow) * KDIM + ko;
      const ushort* wb = wh + (size_t)mrow * KDIM + ko;
      const ushort* wb2 = wl + (size_t)mrow * KDIM + ko;
#pragma unroll
      for (int i = 0; i < 2; ++i)
        rA[i] = *(const float4*)(xb + (size_t)(32 * i) * KDIM);
#pragma unroll
      for (int i = 0; i < 4; ++i) {
        rBh[i] = *(const ushort4*)(wb + (size_t)(32 * i) * KDIM);
        rBl[i] = *(const ushort4*)(wb2 + (size_t)(32 * i) * KDIM);
      }
    }

    short8v ah[2], al[2], bh[4], bl[4];
#pragma unroll
    for (int mi = 0; mi < 2; ++mi) {
      const int row = wr * 32 + mi * 16 + fr;
      ah[mi] = *(const short8v*)&sAh[row][kg];
      al[mi] = *(const short8v*)&sAl[row][kg];
    }
#pragma unroll
    for (int ei = 0; ei < 4; ++ei) {
      const int e = wc * 64 + ei * 16 + fr;
      bh[ei] = *(const short8v*)&sBh[e][kg];
      bl[ei] = *(const short8v*)&sBl[e][kg];
    }
#pragma unroll
    for (int mi = 0; mi < 2; ++mi)
#pragma unroll
      for (int ei = 0; ei < 4; ++ei) {
        acc[mi][ei] = __builtin_amdgcn_mfma_f32_16x16x32_bf16(ah[mi], bh[ei], acc[mi][ei], 0, 0, 0);
        acc[mi][ei] = __builtin_amdgcn_mfma_f32_16x16x32_bf16(ah[mi], bl[ei], acc[mi][ei], 0, 0, 0);
        acc[mi][ei] = __builtin_amdgcn_mfma_f32_16x16x32_bf16(al[mi], bh[ei], acc[mi][ei], 0, 0, 0);
      }
  }

  // C/D layout: e = lane&15, m = (lane>>4)*4 + reg   [m89-verified mapping]
  float* po = part + ((size_t)(inp * splitK + kc) * MDIM + m0) * EDIM;
#pragma unroll
  for (int mi = 0; mi < 2; ++mi) {
    const int mloc = wr * 32 + mi * 16 + ((lane >> 4) << 2);
#pragma unroll
    for (int ei = 0; ei < 4; ++ei) {
      const int e = wc * 64 + ei * 16 + fr;
#pragma unroll
      for (int r = 0; r < 4; ++r)
        po[(size_t)(mloc + r) * EDIM + e] = acc[mi][ei][r];
    }
  }
}

// ---------------- K2: reduce split-K, add bias, per-block BN partial sums ----------------
__global__ __launch_bounds__(256)
void k_reduce(const float* __restrict__ part, const float* __restrict__ bvec,
              float* __restrict__ y, float* __restrict__ spart, int splitK) {
  const int tid = threadIdx.x;
  const int in = blockIdx.z;
  const int rb = blockIdx.x;        // 128 row-blocks of 64 rows
  const int e = tid & 127;
  const int rh = tid >> 7;
  const float bb = bvec[e];
  float s = 0.f, s2 = 0.f;
  for (int rr = 0; rr < 32; ++rr) {
    const int r = rb * 64 + rh * 32 + rr;
    float v = 0.f;
    for (int kc = 0; kc < splitK; ++kc)
      v += part[((size_t)(in * splitK + kc) * MDIM + r) * EDIM + e];
    v += bb;
    y[((size_t)in * MDIM + r) * EDIM + e] = v;
    s += v; s2 += v * v;
  }
  __shared__ float l1[256], l2[256];
  l1[tid] = s; l2[tid] = s2;
  __syncthreads();
  if (rh == 0) {   // deterministic partials (no atomics -> replay-stable)
    s = l1[e] + l1[e + 128];
    s2 = l2[e] + l2[e + 128];
    spart[((size_t)(in * 128 + rb) * 2 + 0) * 128 + e] = s;
    spart[((size_t)(in * 128 + rb) * 2 + 1) * 128 + e] = s2;
  }
}

// ---------------- K3: finalize BN -> folded scale/shift ----------------
__global__ void k_finalize(const float* __restrict__ spart, const float* __restrict__ gamma,
                           const float* __restrict__ beta, float* __restrict__ scsh) {
  const int in = blockIdx.x;   // 0..1
  const int e = threadIdx.x;   // 0..127
  float s = 0.f, s2 = 0.f;
  for (int rb = 0; rb < 128; ++rb) {
    s  += spart[((size_t)(in * 128 + rb) * 2 + 0) * 128 + e];
    s2 += spart[((size_t)(in * 128 + rb) * 2 + 1) * 128 + e];
  }
  const float mu = s * (1.f / MDIM);
  const float var = s2 * (1.f / MDIM) - mu * mu;   // biased, matches reference
  const float rs = rsqrtf(var + 1e-5f);
  const float sc = gamma[e] * rs;
  const float sh = beta[e] - mu * sc;
  scsh[in * 128 + e] = sc;
  scsh[256 + in * 128 + e] = sh;
}

// ---------------- K5: BN+LReLU fused, LDS-staged banded sim + softmax ----------------
// Stages the 4 x-rows + <=34 t-rows in LDS (coalesced, BN applied once per element),
// replacing k_bnapply (deleted) and R8's lane-divergent 512B-stride y reads.
#define SIMW 34
#define SIMP 132   // padded row stride (132 % 32 == 4 -> <=4-way conflict on b128 dot reads)

__global__ __launch_bounds__(256)
void k_sim(const float* __restrict__ y, const float* __restrict__ scsh,
           float* __restrict__ attn, float* __restrict__ aw) {
  const int tid = threadIdx.x;
  const int bid = blockIdx.x;          // 2048 blocks, 4 rows each
  const int b = bid >> 9;              // 512 row-blocks per batch
  const int i0 = (bid << 2) & 2047;
  const int jlo = max(0, i0 - HALF);
  const int jhi = min(NDIM - 1, i0 + 3 + HALF);
  const int tw = jhi - jlo + 1;        // <= 34

  __shared__ float sT[SIMW][SIMP];
  __shared__ float sX[4][SIMP];
  __shared__ float sSc[2][128], sSh[2][128];

  if (tid < 128) { sSc[0][tid] = scsh[tid]; sSh[0][tid] = scsh[256 + tid]; }
  else { const int e = tid - 128; sSc[1][e] = scsh[128 + e]; sSh[1][e] = scsh[384 + e]; }
  __syncthreads();

  // stage + BN + LeakyReLU (each y element transformed exactly once)
  const int totq = (4 + tw) * 32;      // float4 count
  for (int q = tid; q < totq; q += 256) {
    const int rr = q >> 5;
    const int e4 = (q & 31) << 2;
    const bool isx = rr < 4;
    const int gr = isx ? ((b << 11) + i0 + rr)
                       : (MDIM + (b << 11) + jlo + (rr - 4));
    float4 v = *(const float4*)(y + (size_t)gr * EDIM + e4);
    const float* sc = isx ? sSc[0] : sSc[1];
    const float* sh = isx ? sSh[0] : sSh[1];
    const float* pv = (const float*)&v;
    float* dst = isx ? &sX[rr][e4] : &sT[rr - 4][e4];
#pragma unroll
    for (int t = 0; t < 4; ++t) {
      const float val = fmaf(sc[e4 + t], pv[t], sh[e4 + t]);
      dst[t] = val >= 0.f ? val : 0.1f * val;
    }
  }
  __syncthreads();

  const int lane = tid & 63;
  const int wv = tid >> 6;             // wave -> row i0+wv
  const int i = i0 + wv;
  const int row = (b << 11) + i;
  const int jliw = max(0, i - HALF);
  const int jhiw = min(NDIM - 1, i + HALF);
  const int j = jliw + lane;
  const bool valid = (lane < 31) && (j <= jhiw);
  const int trow = (valid ? j : jliw) - jlo;

  float s = 0.f;
#pragma unroll
  for (int e = 0; e < EDIM; e += 4) {
    float4 u = *(const float4*)&sX[wv][e];    // wave-uniform broadcast
    float4 v = *(const float4*)&sT[trow][e];  // <=4-way bank conflict (SIMP=132)
    s = fmaf(u.x, v.x, s); s = fmaf(u.y, v.y, s);
    s = fmaf(u.z, v.z, s); s = fmaf(u.w, v.w, s);
  }
  float sm = valid ? s : -1e30f;
  float mx = sm;
#pragma unroll
  for (int o = 1; o < 64; o <<= 1) mx = fmaxf(mx, __shfl_xor(mx, o));
  const float p = valid ? __expf(sm - mx) : 0.f;
  float ss = p;
#pragma unroll
  for (int o = 1; o < 64; o <<= 1) ss += __shfl_xor(ss, o);
  const float a = p / ss;   // lanes >= 31: p=0 -> a=0

  // full-row write (zeros + band via shfl)
  float* orow = attn + (size_t)row * NDIM;
  const int bw = jhiw - jliw;          // band width - 1 (<= 30)
  for (int c0 = lane << 2; c0 < NDIM; c0 += 256) {
    float4 v;
    float* pv = (float*)&v;
#pragma unroll
    for (int t = 0; t < 4; ++t) {
      const int d = c0 + t - jliw;
      const float val = __shfl(a, d & 63);
      pv[t] = (d >= 0 && d <= bw) ? val : 0.f;
    }
    *(float4*)(orow + c0) = v;
  }
  if (lane < 32) aw[(size_t)row * 32 + lane] = valid ? a : 0.f;
}

// ---------------- K6: banded attn @ mem + blend with sig ----------------
// 1D grid, XCD-chunked: same-XCD consecutive blocks walk i-tiles within one
// (fc,b) slab -> halo rows (30/46) and the 2MB mem slab stay hot in that XCD's L2.
#define TI 16
#define TJMAX 46
#define FC 256
#define NIT (NDIM / TI)          // 128 i-tiles
#define NFC (KDIM / FC)          // 12 f-chunks
#define NWG_MEMW (NIT * NFC * BATCH)   // 6144, divisible by 8

__global__ __launch_bounds__(256, 2)
void k_memw(const float* __restrict__ sig, const float* __restrict__ mem,
            const float* __restrict__ aw, float* __restrict__ out) {
  const int tid = threadIdx.x;
  // bijective XCD-chunked remap (nwg % 8 == 0)
  const int bid = blockIdx.x;
  const int nid = (bid & 7) * (NWG_MEMW / 8) + (bid >> 3);
  const int b  = nid / (NIT * NFC);
  const int r  = nid % (NIT * NFC);
  const int fc0 = (r / NIT) * FC;
  const int i0  = (r % NIT) * TI;      // i fastest within same-XCD chunk
  const int jlo = max(0, i0 - HALF);
  const int jhi = min(NDIM - 1, i0 + TI - 1 + HALF);
  const int tj = jhi - jlo + 1;     // <= 46

  __shared__ float sV[TJMAX][FC];   // mem rows (f-chunk)
  __shared__ float sWt[TJMAX][TI];  // band weights, zeros outside band

  for (int idx = tid; idx < tj * TI; idx += 256) {
    const int jj = idx >> 4;
    const int ii = idx & 15;
    const int ii_g = i0 + ii;
    const int jg = jlo + jj;
    const int jli = max(0, ii_g - HALF);
    const int jhii = min(NDIM - 1, ii_g + HALF);
    float wv = 0.f;
    if (jg >= jli && jg <= jhii) wv = aw[(size_t)((b << 11) + ii_g) * 32 + (jg - jli)];
    sWt[jj][ii] = wv;
  }
  for (int idx = tid; idx < tj * (FC / 4); idx += 256) {
    const int jj = idx >> 6;
    const int f4 = idx & 63;
    *(float4*)&sV[jj][f4 << 2] =
        *(const float4*)(mem + (size_t)((b << 11) + jlo + jj) * KDIM + fc0 + (f4 << 2));
  }
  __syncthreads();

  const int ig = tid >> 6;          // wave id -> 4 i rows
  const int fg = tid & 63;          // lane -> 4 f
  const int ibase = i0 + (ig << 2);
  const int wlo = max(jlo, ibase - HALF) - jlo;
  const int whi = min(jhi, ibase + 3 + HALF) - jlo;

  float acc[4][4];
#pragma unroll
  for (int a = 0; a < 4; ++a)
#pragma unroll
    for (int c = 0; c < 4; ++c) acc[a][c] = 0.f;

  for (int jj = wlo; jj <= whi; ++jj) {   // <= 34 iters, wave-uniform bounds
    float4 wv = *(const float4*)&sWt[jj][ig << 2];   // wave-uniform -> broadcast
    float4 vv = *(const float4*)&sV[jj][fg << 2];    // consecutive -> conflict-free
    const float wa[4] = {wv.x, wv.y, wv.z, wv.w};
    const float va[4] = {vv.x, vv.y, vv.z, vv.w};
#pragma unroll
    for (int mi = 0; mi < 4; ++mi)
#pragma unroll
      for (int fi = 0; fi < 4; ++fi)
        acc[mi][fi] = fmaf(wa[mi], va[fi], acc[mi][fi]);
  }

  const size_t base = (size_t)((b << 11) + ibase) * KDIM + fc0 + (fg << 2);
#pragma unroll
  for (int mi = 0; mi < 4; ++mi) {
    float4 sv = *(const float4*)(sig + base + (size_t)mi * KDIM);
    float4 ov;
    ov.x = 0.5f * sv.x + 0.5f * acc[mi][0];
    ov.y = 0.5f * sv.y + 0.5f * acc[mi][1];
    ov.z = 0.5f * sv.z + 0.5f * acc[mi][2];
    ov.w = 0.5f * sv.w + 0.5f * acc[mi][3];
    *(float4*)(out + base + (size_t)mi * KDIM) = ov;
  }
}

extern "C" void kernel_launch(void* const* d_in, const int* in_sizes, int n_in,
                              void* d_out, int out_size, void* d_ws, size_t ws_size,
                              hipStream_t stream) {
  const float* sig   = (const float*)d_in[0];
  const float* mem   = (const float*)d_in[1];
  const float* w     = (const float*)d_in[2];
  const float* bv    = (const float*)d_in[3];
  const float* gamma = (const float*)d_in[4];
  const float* beta  = (const float*)d_in[5];

  float* out_mem  = (float*)d_out;
  float* out_attn = out_mem + (size_t)BATCH * NDIM * KDIM;   // 25,165,824

  float* wsf = (float*)d_ws;
  const size_t ME = (size_t)MDIM * EDIM;                      // 1,048,576
  // fixed tail (floats): y(2ME) + spart(65536) + scsh(512) + aw(262144) + Wh/Wl(196608)
  const size_t fixed = 2 * ME + 65536 + 512 + 262144 + 196608;
  int splitK = 4;   // R5 measured: splitK=8 regresses (2x epilogue writes, no occupancy gain)
  while (splitK > 1 && ((size_t)2 * splitK * ME + fixed) * 4 > ws_size) splitK >>= 1;

  float* part  = wsf;
  float* y     = part + (size_t)2 * splitK * ME;
  float* spart = y + 2 * ME;
  float* scsh  = spart + 65536;
  float* aw    = scsh + 512;
  ushort* wh   = (ushort*)(aw + 262144);
  ushort* wl   = wh + (size_t)EDIM * KDIM;

  hipLaunchKernelGGL(k_wprep, dim3(EDIM * KDIM / 1024), dim3(256), 0, stream, w, wh, wl);

  dim3 g1(MDIM / BMT, splitK, 2);
  hipLaunchKernelGGL(k_gemm, g1, dim3(256), 0, stream, sig, mem, wh, wl, part, splitK);

  dim3 g2(MDIM / 64, 1, 2);
  hipLaunchKernelGGL(k_reduce, g2, dim3(256), 0, stream, part, bv, y, spart, splitK);

  hipLaunchKernelGGL(k_finalize, dim3(2), dim3(128), 0, stream, spart, gamma, beta, scsh);

  hipLaunchKernelGGL(k_sim, dim3(MDIM / 4), dim3(256), 0, stream, y, scsh, out_attn, aw);

  hipLaunchKernelGGL(k_memw, dim3(NWG_MEMW), dim3(256), 0, stream, sig, mem, aw, out_mem);
}

// Round 11
// 469.902 us; speedup vs baseline: 1.1220x; 1.0086x over previous
//
#include <hip/hip_runtime.h>

#define BATCH 4
#define NDIM 2048
#define EDIM 128
#define KDIM 3072
#define MDIM 8192   // BATCH*NDIM
#define HALF 15

typedef __attribute__((ext_vector_type(8))) short short8v;
typedef __attribute__((ext_vector_type(4))) float f32x4;

__device__ inline ushort bf16h(float x) {   // RNE fp32->bf16
  union { float f; unsigned u; } v; v.f = x;
  unsigned r = v.u + 0x7fff + ((v.u >> 16) & 1);
  return (ushort)(r >> 16);
}

// ---------------- K0: precompute W -> bf16 hi/lo (once; W is L3-resident) ----------------
__global__ __launch_bounds__(256)
void k_wprep(const float* __restrict__ w, ushort* __restrict__ wh, ushort* __restrict__ wl) {
  const int q = (blockIdx.x * 256 + threadIdx.x) * 4;   // 384 blocks cover 393216
  float4 v = *(const float4*)(w + q);
  const float f[4] = {v.x, v.y, v.z, v.w};
  ushort4 h, l;
  ushort* ph = (ushort*)&h; ushort* pl = (ushort*)&l;
#pragma unroll
  for (int j = 0; j < 4; ++j) {
    unsigned u = __float_as_uint(f[j]);
    ph[j] = (ushort)(u >> 16);                              // truncation hi
    pl[j] = bf16h(f[j] - __uint_as_float(u & 0xffff0000u)); // exact residual, RNE
  }
  *(ushort4*)(wh + q) = h;
  *(ushort4*)(wl + q) = l;
}

// ---------------- K1: MFMA bf16 hi/lo-split GEMM, BK=64, swizzled LDS ----------------
// R9 measured: structure-bound (MfmaUtil 13%, both pipes idle). Fix: 96 MFMA/wave per
// barrier-pair (BK=64), halved barriers, T2 XOR-swizzle (old layout was 8-way conflicted).
#define BMT 128
#define BK 64
// ushort index into a [row][BK] plane with 16B-chunk XOR swizzle
#define SWZ(row, k) (((row) << 6) + (((((k) >> 3) ^ ((row) & 7)) << 3) | ((k) & 7)))

__global__ __launch_bounds__(256, 2)
void k_gemm(const float* __restrict__ x0, const float* __restrict__ x1,
            const ushort* __restrict__ wh, const ushort* __restrict__ wl,
            float* __restrict__ part, int splitK) {
  const int tid = threadIdx.x;
  const int m0 = blockIdx.x * BMT;
  const int kc = blockIdx.y;
  const int inp = blockIdx.z;
  const float* __restrict__ x = inp ? x1 : x0;
  const int kpc = KDIM / splitK;
  const int kbeg = kc * kpc;
  const int nsteps = kpc / BK;      // 12 at splitK=4

  __shared__ ushort sAh[BMT * BK];  // 16KB each, 64KB total -> 2 blocks/CU
  __shared__ ushort sAl[BMT * BK];
  __shared__ ushort sBh[EDIM * BK];
  __shared__ ushort sBl[EDIM * BK];

  // staging map: thread t -> rows (t>>2), (t>>2)+64; k-span (t&3)*16 .. +16
  const int srow = tid >> 2;
  const int skb = (tid & 3) << 4;

  // compute map: 4 waves 2x2, wave = 64m x 64e = 4x4 fragments
  const int lane = tid & 63;
  const int wid = tid >> 6;
  const int wr = wid >> 1;
  const int wc = wid & 1;
  const int fr = lane & 15;
  const int kg = (lane >> 4) << 3;   // 0,8,16,24

  f32x4 acc[4][4];
#pragma unroll
  for (int a = 0; a < 4; ++a)
#pragma unroll
    for (int b = 0; b < 4; ++b) acc[a][b] = (f32x4){0.f, 0.f, 0.f, 0.f};

  float4 rA[2][4];
  ushort4 rBh[2][4], rBl[2][4];
  {
    const float* xb = x + (size_t)(m0 + srow) * KDIM + kbeg + skb;
    const ushort* wb = wh + (size_t)srow * KDIM + kbeg + skb;
    const ushort* wb2 = wl + (size_t)srow * KDIM + kbeg + skb;
#pragma unroll
    for (int h = 0; h < 2; ++h)
#pragma unroll
      for (int j = 0; j < 4; ++j) {
        rA[h][j]  = *(const float4*)(xb + (size_t)(64 * h) * KDIM + 4 * j);
        rBh[h][j] = *(const ushort4*)(wb + (size_t)(64 * h) * KDIM + 4 * j);
        rBl[h][j] = *(const ushort4*)(wb2 + (size_t)(64 * h) * KDIM + 4 * j);
      }
  }

  for (int st = 0; st < nsteps; ++st) {
    __syncthreads();   // consumers of previous tile done
#pragma unroll
    for (int h = 0; h < 2; ++h) {
      const int row = srow + 64 * h;
#pragma unroll
      for (int j = 0; j < 4; ++j) {
        const int k = skb + 4 * j;
        const float fa[4] = {rA[h][j].x, rA[h][j].y, rA[h][j].z, rA[h][j].w};
        ushort4 ah, al;
        ushort* pah = (ushort*)&ah; ushort* pal = (ushort*)&al;
#pragma unroll
        for (int t = 0; t < 4; ++t) {
          unsigned u = __float_as_uint(fa[t]);
          pah[t] = (ushort)(u >> 16);
          pal[t] = bf16h(fa[t] - __uint_as_float(u & 0xffff0000u));
        }
        *(ushort4*)&sAh[SWZ(row, k)] = ah;
        *(ushort4*)&sAl[SWZ(row, k)] = al;
        *(ushort4*)&sBh[SWZ(row, k)] = rBh[h][j];
        *(ushort4*)&sBl[SWZ(row, k)] = rBl[h][j];
      }
    }
    __syncthreads();

    if (st + 1 < nsteps) {   // prefetch next tile under compute (T14)
      const int ko = kbeg + (st + 1) * BK + skb;
      const float* xb = x + (size_t)(m0 + srow) * KDIM + ko;
      const ushort* wb = wh + (size_t)srow * KDIM + ko;
      const ushort* wb2 = wl + (size_t)srow * KDIM + ko;
#pragma unroll
      for (int h = 0; h < 2; ++h)
#pragma unroll
        for (int j = 0; j < 4; ++j) {
          rA[h][j]  = *(const float4*)(xb + (size_t)(64 * h) * KDIM + 4 * j);
          rBh[h][j] = *(const ushort4*)(wb + (size_t)(64 * h) * KDIM + 4 * j);
          rBl[h][j] = *(const ushort4*)(wb2 + (size_t)(64 * h) * KDIM + 4 * j);
        }
    }

#pragma unroll
    for (int kk = 0; kk < 2; ++kk) {
      const int kb2 = kg + 32 * kk;
      short8v ah[4], al[4], bh[4], bl[4];
#pragma unroll
      for (int mi = 0; mi < 4; ++mi) {
        const int row = wr * 64 + mi * 16 + fr;
        ah[mi] = *(const short8v*)&sAh[SWZ(row, kb2)];
        al[mi] = *(const short8v*)&sAl[SWZ(row, kb2)];
      }
#pragma unroll
      for (int ei = 0; ei < 4; ++ei) {
        const int e = wc * 64 + ei * 16 + fr;
        bh[ei] = *(const short8v*)&sBh[SWZ(e, kb2)];
        bl[ei] = *(const short8v*)&sBl[SWZ(e, kb2)];
      }
#pragma unroll
      for (int mi = 0; mi < 4; ++mi)
#pragma unroll
        for (int ei = 0; ei < 4; ++ei) {
          acc[mi][ei] = __builtin_amdgcn_mfma_f32_16x16x32_bf16(ah[mi], bh[ei], acc[mi][ei], 0, 0, 0);
          acc[mi][ei] = __builtin_amdgcn_mfma_f32_16x16x32_bf16(ah[mi], bl[ei], acc[mi][ei], 0, 0, 0);
          acc[mi][ei] = __builtin_amdgcn_mfma_f32_16x16x32_bf16(al[mi], bh[ei], acc[mi][ei], 0, 0, 0);
        }
    }
  }

  // C/D layout: e = lane&15, m = (lane>>4)*4 + reg   [m89-verified mapping]
  float* po = part + ((size_t)(inp * splitK + kc) * MDIM + m0) * EDIM;
#pragma unroll
  for (int mi = 0; mi < 4; ++mi) {
    const int mloc = wr * 64 + mi * 16 + ((lane >> 4) << 2);
#pragma unroll
    for (int ei = 0; ei < 4; ++ei) {
      const int e = wc * 64 + ei * 16 + fr;
#pragma unroll
      for (int r = 0; r < 4; ++r)
        po[(size_t)(mloc + r) * EDIM + e] = acc[mi][ei][r];
    }
  }
}

// ---------------- K2: reduce split-K, add bias, per-block BN partial sums ----------------
__global__ __launch_bounds__(256)
void k_reduce(const float* __restrict__ part, const float* __restrict__ bvec,
              float* __restrict__ y, float* __restrict__ spart, int splitK) {
  const int tid = threadIdx.x;
  const int in = blockIdx.z;
  const int rb = blockIdx.x;        // 128 row-blocks of 64 rows
  const int e = tid & 127;
  const int rh = tid >> 7;
  const float bb = bvec[e];
  float s = 0.f, s2 = 0.f;
  for (int rr = 0; rr < 32; ++rr) {
    const int r = rb * 64 + rh * 32 + rr;
    float v = 0.f;
    for (int kc = 0; kc < splitK; ++kc)
      v += part[((size_t)(in * splitK + kc) * MDIM + r) * EDIM + e];
    v += bb;
    y[((size_t)in * MDIM + r) * EDIM + e] = v;
    s += v; s2 += v * v;
  }
  __shared__ float l1[256], l2[256];
  l1[tid] = s; l2[tid] = s2;
  __syncthreads();
  if (rh == 0) {   // deterministic partials (no atomics -> replay-stable)
    s = l1[e] + l1[e + 128];
    s2 = l2[e] + l2[e + 128];
    spart[((size_t)(in * 128 + rb) * 2 + 0) * 128 + e] = s;
    spart[((size_t)(in * 128 + rb) * 2 + 1) * 128 + e] = s2;
  }
}

// ---------------- K3: finalize BN -> folded scale/shift ----------------
__global__ void k_finalize(const float* __restrict__ spart, const float* __restrict__ gamma,
                           const float* __restrict__ beta, float* __restrict__ scsh) {
  const int in = blockIdx.x;   // 0..1
  const int e = threadIdx.x;   // 0..127
  float s = 0.f, s2 = 0.f;
  for (int rb = 0; rb < 128; ++rb) {
    s  += spart[((size_t)(in * 128 + rb) * 2 + 0) * 128 + e];
    s2 += spart[((size_t)(in * 128 + rb) * 2 + 1) * 128 + e];
  }
  const float mu = s * (1.f / MDIM);
  const float var = s2 * (1.f / MDIM) - mu * mu;   // biased, matches reference
  const float rs = rsqrtf(var + 1e-5f);
  const float sc = gamma[e] * rs;
  const float sh = beta[e] - mu * sc;
  scsh[in * 128 + e] = sc;
  scsh[256 + in * 128 + e] = sh;
}

// ---------------- K5: BN+LReLU fused, LDS-staged banded sim + softmax ----------------
#define SIMW 34
#define SIMP 132   // padded row stride

__global__ __launch_bounds__(256)
void k_sim(const float* __restrict__ y, const float* __restrict__ scsh,
           float* __restrict__ attn, float* __restrict__ aw) {
  const int tid = threadIdx.x;
  const int bid = blockIdx.x;          // 2048 blocks, 4 rows each
  const int b = bid >> 9;              // 512 row-blocks per batch
  const int i0 = (bid << 2) & 2047;
  const int jlo = max(0, i0 - HALF);
  const int jhi = min(NDIM - 1, i0 + 3 + HALF);
  const int tw = jhi - jlo + 1;        // <= 34

  __shared__ float sT[SIMW][SIMP];
  __shared__ float sX[4][SIMP];
  __shared__ float sSc[2][128], sSh[2][128];

  if (tid < 128) { sSc[0][tid] = scsh[tid]; sSh[0][tid] = scsh[256 + tid]; }
  else { const int e = tid - 128; sSc[1][e] = scsh[128 + e]; sSh[1][e] = scsh[384 + e]; }
  __syncthreads();

  // stage + BN + LeakyReLU (each y element transformed exactly once)
  const int totq = (4 + tw) * 32;      // float4 count
  for (int q = tid; q < totq; q += 256) {
    const int rr = q >> 5;
    const int e4 = (q & 31) << 2;
    const bool isx = rr < 4;
    const int gr = isx ? ((b << 11) + i0 + rr)
                       : (MDIM + (b << 11) + jlo + (rr - 4));
    float4 v = *(const float4*)(y + (size_t)gr * EDIM + e4);
    const float* sc = isx ? sSc[0] : sSc[1];
    const float* sh = isx ? sSh[0] : sSh[1];
    const float* pv = (const float*)&v;
    float* dst = isx ? &sX[rr][e4] : &sT[rr - 4][e4];
#pragma unroll
    for (int t = 0; t < 4; ++t) {
      const float val = fmaf(sc[e4 + t], pv[t], sh[e4 + t]);
      dst[t] = val >= 0.f ? val : 0.1f * val;
    }
  }
  __syncthreads();

  const int lane = tid & 63;
  const int wv = tid >> 6;             // wave -> row i0+wv
  const int i = i0 + wv;
  const int row = (b << 11) + i;
  const int jliw = max(0, i - HALF);
  const int jhiw = min(NDIM - 1, i + HALF);
  const int j = jliw + lane;
  const bool valid = (lane < 31) && (j <= jhiw);
  const int trow = (valid ? j : jliw) - jlo;

  float s = 0.f;
#pragma unroll
  for (int e = 0; e < EDIM; e += 4) {
    float4 u = *(const float4*)&sX[wv][e];    // wave-uniform broadcast
    float4 v = *(const float4*)&sT[trow][e];
    s = fmaf(u.x, v.x, s); s = fmaf(u.y, v.y, s);
    s = fmaf(u.z, v.z, s); s = fmaf(u.w, v.w, s);
  }
  float sm = valid ? s : -1e30f;
  float mx = sm;
#pragma unroll
  for (int o = 1; o < 64; o <<= 1) mx = fmaxf(mx, __shfl_xor(mx, o));
  const float p = valid ? __expf(sm - mx) : 0.f;
  float ss = p;
#pragma unroll
  for (int o = 1; o < 64; o <<= 1) ss += __shfl_xor(ss, o);
  const float a = p / ss;   // lanes >= 31: p=0 -> a=0

  // full-row write (zeros + band via shfl)
  float* orow = attn + (size_t)row * NDIM;
  const int bw = jhiw - jliw;          // band width - 1 (<= 30)
  for (int c0 = lane << 2; c0 < NDIM; c0 += 256) {
    float4 v;
    float* pv = (float*)&v;
#pragma unroll
    for (int t = 0; t < 4; ++t) {
      const int d = c0 + t - jliw;
      const float val = __shfl(a, d & 63);
      pv[t] = (d >= 0 && d <= bw) ? val : 0.f;
    }
    *(float4*)(orow + c0) = v;
  }
  if (lane < 32) aw[(size_t)row * 32 + lane] = valid ? a : 0.f;
}

// ---------------- K6: banded attn @ mem + blend; one block per (i-tile,b), fc looped ----------------
// 512 blocks XCD-chunked: same-XCD neighbors = adjacent i-tiles -> 30/46 halo rows L2-hot.
#define TI 16
#define TJMAX 46
#define FCW 256
#define NWG2 (NDIM / TI * BATCH)   // 512

__global__ __launch_bounds__(256, 2)
void k_memw(const float* __restrict__ sig, const float* __restrict__ mem,
            const float* __restrict__ aw, float* __restrict__ out) {
  const int tid = threadIdx.x;
  const int bid = blockIdx.x;
  const int nid = (bid & 7) * (NWG2 / 8) + (bid >> 3);   // bijective (512 % 8 == 0)
  const int b = nid >> 7;
  const int i0 = (nid & 127) << 4;
  const int jlo = max(0, i0 - HALF);
  const int jhi = min(NDIM - 1, i0 + TI - 1 + HALF);
  const int tj = jhi - jlo + 1;     // <= 46

  __shared__ float sV[TJMAX][FCW];  // 47KB
  __shared__ float sWt[TJMAX][TI];  // 3KB

  for (int idx = tid; idx < tj * TI; idx += 256) {
    const int jj = idx >> 4;
    const int ii = idx & 15;
    const int ii_g = i0 + ii;
    const int jg = jlo + jj;
    const int jli = max(0, ii_g - HALF);
    const int jhii = min(NDIM - 1, ii_g + HALF);
    float wv = 0.f;
    if (jg >= jli && jg <= jhii) wv = aw[(size_t)((b << 11) + ii_g) * 32 + (jg - jli)];
    sWt[jj][ii] = wv;
  }
  // (sWt consumed only after the first in-loop barrier)

  const int ig = tid >> 6;          // wave id -> 4 i rows
  const int fg = tid & 63;          // lane -> 4 f
  const int ibase = i0 + (ig << 2);
  const int wlo = max(jlo, ibase - HALF) - jlo;
  const int whi = min(jhi, ibase + 3 + HALF) - jlo;

  for (int fc0 = 0; fc0 < KDIM; fc0 += FCW) {
    for (int idx = tid; idx < tj * (FCW / 4); idx += 256) {
      const int jj = idx >> 6;
      const int f4 = idx & 63;
      *(float4*)&sV[jj][f4 << 2] =
          *(const float4*)(mem + (size_t)((b << 11) + jlo + jj) * KDIM + fc0 + (f4 << 2));
    }
    __syncthreads();

    float acc[4][4];
#pragma unroll
    for (int a = 0; a < 4; ++a)
#pragma unroll
      for (int c = 0; c < 4; ++c) acc[a][c] = 0.f;

    for (int jj = wlo; jj <= whi; ++jj) {   // <= 34 iters, wave-uniform bounds
      float4 wv = *(const float4*)&sWt[jj][ig << 2];   // wave-uniform -> broadcast
      float4 vv = *(const float4*)&sV[jj][fg << 2];    // consecutive -> conflict-free
      const float wa[4] = {wv.x, wv.y, wv.z, wv.w};
      const float va[4] = {vv.x, vv.y, vv.z, vv.w};
#pragma unroll
      for (int mi = 0; mi < 4; ++mi)
#pragma unroll
        for (int fi = 0; fi < 4; ++fi)
          acc[mi][fi] = fmaf(wa[mi], va[fi], acc[mi][fi]);
    }

    const size_t base = (size_t)((b << 11) + ibase) * KDIM + fc0 + (fg << 2);
#pragma unroll
    for (int mi = 0; mi < 4; ++mi) {
      float4 sv = *(const float4*)(sig + base + (size_t)mi * KDIM);
      float4 ov;
      ov.x = 0.5f * sv.x + 0.5f * acc[mi][0];
      ov.y = 0.5f * sv.y + 0.5f * acc[mi][1];
      ov.z = 0.5f * sv.z + 0.5f * acc[mi][2];
      ov.w = 0.5f * sv.w + 0.5f * acc[mi][3];
      *(float4*)(out + base + (size_t)mi * KDIM) = ov;
    }
    __syncthreads();   // protect sV before next chunk
  }
}

extern "C" void kernel_launch(void* const* d_in, const int* in_sizes, int n_in,
                              void* d_out, int out_size, void* d_ws, size_t ws_size,
                              hipStream_t stream) {
  const float* sig   = (const float*)d_in[0];
  const float* mem   = (const float*)d_in[1];
  const float* w     = (const float*)d_in[2];
  const float* bv    = (const float*)d_in[3];
  const float* gamma = (const float*)d_in[4];
  const float* beta  = (const float*)d_in[5];

  float* out_mem  = (float*)d_out;
  float* out_attn = out_mem + (size_t)BATCH * NDIM * KDIM;   // 25,165,824

  float* wsf = (float*)d_ws;
  const size_t ME = (size_t)MDIM * EDIM;                      // 1,048,576
  const size_t fixed = 2 * ME + 65536 + 512 + 262144 + 196608;
  int splitK = 4;   // R5: splitK=8 regresses (2x epilogue writes)
  while (splitK > 1 && ((size_t)2 * splitK * ME + fixed) * 4 > ws_size) splitK >>= 1;

  float* part  = wsf;
  float* y     = part + (size_t)2 * splitK * ME;
  float* spart = y + 2 * ME;
  float* scsh  = spart + 65536;
  float* aw    = scsh + 512;
  ushort* wh   = (ushort*)(aw + 262144);
  ushort* wl   = wh + (size_t)EDIM * KDIM;

  hipLaunchKernelGGL(k_wprep, dim3(EDIM * KDIM / 1024), dim3(256), 0, stream, w, wh, wl);

  dim3 g1(MDIM / BMT, splitK, 2);
  hipLaunchKernelGGL(k_gemm, g1, dim3(256), 0, stream, sig, mem, wh, wl, part, splitK);

  dim3 g2(MDIM / 64, 1, 2);
  hipLaunchKernelGGL(k_reduce, g2, dim3(256), 0, stream, part, bv, y, spart, splitK);

  hipLaunchKernelGGL(k_finalize, dim3(2), dim3(128), 0, stream, spart, gamma, beta, scsh);

  hipLaunchKernelGGL(k_sim, dim3(MDIM / 4), dim3(256), 0, stream, y, scsh, out_attn, aw);

  hipLaunchKernelGGL(k_memw, dim3(NWG2), dim3(256), 0, stream, sig, mem, aw, out_mem);
}